// Round 10
// baseline (243.318 us; speedup 1.0000x reference)
//
#include <hip/hip_runtime.h>
#include <hip/hip_bf16.h>

// Problem constants
#define BB   4096
#define INW  1024
#define HH   1024
#define KIN  2048      // IN + H
#define NG   5120      // 3H + 2H
#define KH   32        // inner hidden
#define FPG  10        // 16-col fragments per 160-col gate-group
#define NTG  32        // number of gate-groups (= H/32)

typedef __bf16 bf16;
typedef __bf16 bf16x4 __attribute__((ext_vector_type(4)));
typedef __bf16 bf16x8 __attribute__((ext_vector_type(8)));
typedef float  floatx4 __attribute__((ext_vector_type(4)));

#define GLD16(gp, lp)                                                          \
  __builtin_amdgcn_global_load_lds(                                            \
      (__attribute__((address_space(1))) const void*)(gp),                     \
      (__attribute__((address_space(3))) void*)(lp), 16, 0, 0)

// ---------------------------------------------------------------------------
// 1. prep (unchanged — sequential-row B shuffle, coalesced comb).
//    Wb chunk layout [F][kk][lane] with F = nt*10+f: chunk = (F*64 + kk)*64 +
//    (kq*16 + s) holds B[hcol = nt*32 + (f/5)*16 + s, gate f%5]
//    [k = kk*32 + kq*8 .. +7].
// ---------------------------------------------------------------------------
#define NCB  4096      // comb blocks: BB*KIN/8 threads / 256
#define NWB  1280      // Wb blocks: 32 nt x 10 f x 4 row-quarters

__global__ __launch_bounds__(256) void prep(
    const float* __restrict__ x, const float* __restrict__ h,
    const float* __restrict__ Wg, const float* __restrict__ Wc,
    bf16* __restrict__ comb, bf16* __restrict__ Wb) {
  int tid = threadIdx.x;
  if (blockIdx.x < NCB) {              // ---- comb: concat + cast ----
    int e = (blockIdx.x * 256 + tid) * 8;
    int b = e >> 11;          // / KIN
    int c = e & (KIN - 1);
    const float* src = (c < INW) ? (x + (size_t)b * INW + c)
                                 : (h + (size_t)b * HH + (c - INW));
    float4 v0 = *(const float4*)src;
    float4 v1 = *(const float4*)(src + 4);
    bf16x8 ov;
    ov[0] = (bf16)v0.x; ov[1] = (bf16)v0.y; ov[2] = (bf16)v0.z; ov[3] = (bf16)v0.w;
    ov[4] = (bf16)v1.x; ov[5] = (bf16)v1.y; ov[6] = (bf16)v1.z; ov[7] = (bf16)v1.w;
    *(bf16x8*)(comb + e) = ov;
  } else {                             // ---- Wb: sequential-row shuffle ----
    int w   = blockIdx.x - NCB;        // [0, 1280)
    int nt  = w / 40;
    int rem = w - nt * 40;
    int f   = rem >> 2;                // fragment slot 0..9
    int rp  = rem & 3;                 // row-quarter 0..3
    int q   = f / 5;
    int g   = f - q * 5;               // gate: 0=i 1=f 2=o 3=p0 4=p1
    int kk  = tid >> 2;                // k-chunk of 32
    int kq  = tid & 3;                 // k-quad within chunk
    size_t wbase = ((size_t)(nt * FPG + f) * 64 + kk) * 64 + kq * 16;
#pragma unroll
    for (int r4 = 0; r4 < 4; ++r4) {
      int s    = rp * 4 + r4;          // row-in-fragment 0..15
      int hcol = nt * 32 + q * 16 + s;
      const float* src = (g < 3)
          ? (Wg + (size_t)(g * HH + hcol) * KIN + tid * 8)
          : (Wc + (size_t)(2 * hcol + (g - 3)) * KIN + tid * 8);
      float4 v0 = *(const float4*)src;
      float4 v1 = *(const float4*)(src + 4);
      bf16x8 ov;
      ov[0] = (bf16)v0.x; ov[1] = (bf16)v0.y; ov[2] = (bf16)v0.z; ov[3] = (bf16)v0.w;
      ov[4] = (bf16)v1.x; ov[5] = (bf16)v1.y; ov[6] = (bf16)v1.z; ov[7] = (bf16)v1.w;
      *(bf16x8*)(Wb + (wbase + s) * 8) = ov;
    }
  }
}

// ---------------------------------------------------------------------------
// 2. Fused GEMM + LSTM epilogue. R10 = R9 geometry + R5 double-buffering.
//    R9 post-mortem: occupancy fix confirmed (4 waves/SIMD, MfmaUtil 31->35,
//    dur 117.6->107) but it reverted to the single-buffered loop, so the
//    per-iteration vmcnt(0) staging drain is exposed again. The two proven
//    levers have never been combined: R5 had pipeline at 2 waves/SIMD
//    (112us), R9 has 4 waves/SIMD unpipelined (107us).
//    Now: 2 x 36 KB LDS buffers = 72 KB/block; 2 blocks/CU = 144 <= 160 KB,
//    so 16 waves/CU SURVIVES double-buffering (registers untouched, 60 VGPR
//    vs 128 cap). Schedule: prologue STAGE(0); per iter { STAGE(buf^1, t+1);
//    COMPUTE(buf); sync } — prefetch has the whole 40-MFMA phase in flight,
//    drain covered by 4 waves/SIMD at independent phases.
//    Spill tripwire: WRITE_SIZE must stay ~33 MB.
// ---------------------------------------------------------------------------
#define ASZ  8192      // A elems per buffer (16 KB)
#define BSZ  10240     // B elems per buffer (20 KB)
#define BUF  (ASZ + BSZ)

__global__ __launch_bounds__(512, 4) void gemm_fused(
    const bf16* __restrict__ A, const bf16* __restrict__ Bm,
    const float* __restrict__ c_prev, const float* __restrict__ bg,
    const float* __restrict__ bc, const float* __restrict__ W1,
    const float* __restrict__ b1, const float* __restrict__ W2,
    const float* __restrict__ b2, float* __restrict__ h_next,
    float* __restrict__ c_next) {
  __shared__ bf16 sh[2 * BUF];     // 72 KB: two {A 16K + B 20K} buffers

  const int tid  = threadIdx.x;
  const int wave = tid >> 6;
  const int lane = tid & 63;

  // R5 XCD swizzle (proven): 1024 blocks, 8 XCDs, 128 blocks/XCD, m fastest.
  const int bid = blockIdx.y * gridDim.x + blockIdx.x;
  const int swz = (bid & 7) * 128 + (bid >> 3);
  const int m0  = (swz & 31) * 128;
  const int nt  = swz >> 5;

  const int wm = (wave >> 1) * 32;   // wave row origin (4 row-groups of 32)
  const int q  = wave & 1;           // wave col half: which 16 h's
  const int lr = lane & 15;
  const int qd = lane >> 4;

  floatx4 acc[2][5] = {};

  // ---- STAGE(bb, kt): role-split staging into buffer bb ----
  // waves 0-3: A, 1024 slots (128 rows x 8 chunks), XOR-swizzled
  // waves 4-7: B, 1280 slots (20 chunks of 1 KB), linear
#define STAGE(bb, kt)                                                          \
  {                                                                            \
    if (wave < 4) {                                                            \
      _Pragma("unroll")                                                        \
      for (int j = 0; j < 4; ++j) {                                            \
        int s   = j * 256 + tid;                                               \
        int row = s >> 3;                                                      \
        int c   = (s & 7) ^ (row & 7);                                         \
        GLD16(A + (size_t)(m0 + row) * KIN + (kt) * 64 + c * 8,                \
              sh + (size_t)(bb) * BUF + (size_t)(j * 256 + wave * 64) * 8);    \
      }                                                                        \
    } else {                                                                   \
      int wv = wave - 4;                                                       \
      _Pragma("unroll")                                                        \
      for (int j = 0; j < 5; ++j) {                                            \
        int s   = j * 256 + wv * 64 + lane;                                    \
        int c20 = s >> 6;                                                      \
        int f   = c20 >> 1;                                                    \
        int ks  = c20 & 1;                                                     \
        size_t gchunk = (size_t)(nt * FPG + f) * 64 + ((kt) * 2 + ks);         \
        GLD16(Bm + (gchunk * 64 + lane) * 8,                                   \
              sh + (size_t)(bb) * BUF + ASZ + (size_t)s * 8);                  \
      }                                                                        \
    }                                                                          \
  }

  // ---- COMPUTE(bb): 2 k-steps x 10 MFMA per wave from buffer bb ----
#define COMPUTE(bb)                                                            \
  {                                                                            \
    const bf16* As = sh + (size_t)(bb) * BUF;                                  \
    const bf16* Bs = As + ASZ;                                                 \
    _Pragma("unroll")                                                          \
    for (int ks = 0; ks < 2; ++ks) {                                           \
      bf16x8 af[2];                                                            \
      _Pragma("unroll")                                                        \
      for (int mi = 0; mi < 2; ++mi) {                                         \
        int row  = wm + mi * 16 + lr;                                          \
        int slot = (ks * 4 + qd) ^ (lr & 7);                                   \
        af[mi] = *(const bf16x8*)&As[(row << 6) + (slot << 3)];                \
      }                                                                        \
      bf16x8 bfr[5];                                                           \
      _Pragma("unroll")                                                        \
      for (int ni = 0; ni < 5; ++ni) {                                         \
        int chunk = ((q * 5 + ni) << 1) + ks;                                  \
        bfr[ni] = *(const bf16x8*)&Bs[(chunk << 9) + (lane << 3)];             \
      }                                                                        \
      _Pragma("unroll")                                                        \
      for (int mi = 0; mi < 2; ++mi)                                           \
        _Pragma("unroll")                                                      \
        for (int ni = 0; ni < 5; ++ni)                                         \
          acc[mi][ni] = __builtin_amdgcn_mfma_f32_16x16x32_bf16(               \
              af[mi], bfr[ni], acc[mi][ni], 0, 0, 0);                          \
    }                                                                          \
  }

  // Prologue: stage tile 0 into buffer 0, drain, barrier.
  STAGE(0, 0);
  __syncthreads();   // vmcnt(0) lgkmcnt(0) + s_barrier

  // 2-phase pipeline: 31 iterations + tail.
  for (int kt = 0; kt < KIN / 64 - 1; ++kt) {
    const int cur = kt & 1;
    STAGE(cur ^ 1, kt + 1);   // next tile in flight through compute
    COMPUTE(cur);
    __syncthreads();          // drains t+1 loads; cur buffer free
  }
  COMPUTE(1);                 // tile 31 (31 & 1 = 1), no prefetch

  // ---- fused epilogue: all 5 gates of (b, h) live in this lane ----
  const int h   = nt * 32 + q * 16 + lr;
  const float bgi = bg[h];
  const float bgf = bg[HH + h];
  const float bgo = bg[2 * HH + h];
  const float bc0 = bc[2 * h];
  const float bc1 = bc[2 * h + 1];
  const float gb  = b2[0];

  float p0[8], p1[8], ga[8];
#pragma unroll
  for (int mi = 0; mi < 2; ++mi)
#pragma unroll
    for (int r = 0; r < 4; ++r) {
      p0[mi * 4 + r] = acc[mi][3][r] + bc0;
      p1[mi * 4 + r] = acc[mi][4][r] + bc1;
      ga[mi * 4 + r] = gb;
    }
  // inner MLP: k-outer so the 4 uniform weight scalars stay in SGPRs
#pragma unroll
  for (int k = 0; k < KH; ++k) {
    float w0 = W1[2 * k], w1 = W1[2 * k + 1], bk = b1[k], wk = W2[k];
#pragma unroll
    for (int e = 0; e < 8; ++e) {
      float hv = fmaf(p0[e], w0, fmaf(p1[e], w1, bk));
      hv = fmaxf(hv, 0.0f);
      ga[e] = fmaf(hv, wk, ga[e]);
    }
  }

#pragma unroll
  for (int mi = 0; mi < 2; ++mi)
#pragma unroll
    for (int r = 0; r < 4; ++r) {
      int b    = m0 + wm + mi * 16 + qd * 4 + r;
      size_t o = (size_t)b * HH + h;
      float si = 1.0f / (1.0f + __expf(-(acc[mi][0][r] + bgi)));
      float sf = 1.0f / (1.0f + __expf(-(acc[mi][1][r] + bgf)));
      float so = 1.0f / (1.0f + __expf(-(acc[mi][2][r] + bgo)));
      float cn = fmaf(sf, c_prev[o], si * ga[mi * 4 + r]);
      float e2 = __expf(2.0f * cn);          // tanh(cn) = 1 - 2/(e^{2cn}+1)
      float th = 1.0f - 2.0f / (e2 + 1.0f);
      h_next[o] = so * th;
      c_next[o] = cn;
    }
}

// ---------------------------------------------------------------------------
extern "C" void kernel_launch(void* const* d_in, const int* in_sizes, int n_in,
                              void* d_out, int out_size, void* d_ws, size_t ws_size,
                              hipStream_t stream) {
  const float* x      = (const float*)d_in[0];
  const float* h_prev = (const float*)d_in[1];
  const float* c_prev = (const float*)d_in[2];
  const float* Wg     = (const float*)d_in[3];
  const float* bg     = (const float*)d_in[4];
  const float* Wc     = (const float*)d_in[5];
  const float* bc     = (const float*)d_in[6];
  const float* W1     = (const float*)d_in[7];
  const float* b1     = (const float*)d_in[8];
  const float* W2     = (const float*)d_in[9];
  const float* b2     = (const float*)d_in[10];
  float* out = (float*)d_out;

  // workspace layout
  char* ws = (char*)d_ws;
  bf16* comb = (bf16*)ws;                                    // 16 MB
  bf16* Wb   = (bf16*)(ws + (size_t)BB * KIN * 2);           // 20 MB

  // 1. prep (concat + cast + gate-permuted, sequential-read B shuffle)
  prep<<<NCB + NWB, 256, 0, stream>>>(x, h_prev, Wg, Wc, comb, Wb);

  // 2. fused GEMM + epilogue (8-wave geometry + 2-phase double-buffer)
  dim3 grid(BB / 128, NTG);
  gemm_fused<<<grid, 512, 0, stream>>>(comb, Wb, c_prev, bg, bc, W1, b1, W2,
                                       b2, out, out + (size_t)BB * HH);
}

// Round 11
// 240.864 us; speedup vs baseline: 1.0102x; 1.0102x over previous
//
#include <hip/hip_runtime.h>
#include <hip/hip_bf16.h>

// Problem constants
#define BB   4096
#define INW  1024
#define HH   1024
#define KIN  2048      // IN + H
#define NG   5120      // 3H + 2H
#define KH   32        // inner hidden
#define FPG  10        // 16-col fragments per 160-col gate-group
#define NTG  32        // number of gate-groups (= H/32)

typedef __bf16 bf16;
typedef __bf16 bf16x4 __attribute__((ext_vector_type(4)));
typedef __bf16 bf16x8 __attribute__((ext_vector_type(8)));
typedef float  floatx4 __attribute__((ext_vector_type(4)));

#define GLD16(gp, lp)                                                          \
  __builtin_amdgcn_global_load_lds(                                            \
      (__attribute__((address_space(1))) const void*)(gp),                     \
      (__attribute__((address_space(3))) void*)(lp), 16, 0, 0)

// ---------------------------------------------------------------------------
// 1. prep (unchanged — sequential-row B shuffle, coalesced comb).
//    Wb chunk layout [F][kk][lane] with F = nt*10+f: chunk = (F*64 + kk)*64 +
//    (kq*16 + s) holds B[hcol = nt*32 + (f/5)*16 + s, gate f%5]
//    [k = kk*32 + kq*8 .. +7].
// ---------------------------------------------------------------------------
#define NCB  4096      // comb blocks: BB*KIN/8 threads / 256
#define NWB  1280      // Wb blocks: 32 nt x 10 f x 4 row-quarters

__global__ __launch_bounds__(256) void prep(
    const float* __restrict__ x, const float* __restrict__ h,
    const float* __restrict__ Wg, const float* __restrict__ Wc,
    bf16* __restrict__ comb, bf16* __restrict__ Wb) {
  int tid = threadIdx.x;
  if (blockIdx.x < NCB) {              // ---- comb: concat + cast ----
    int e = (blockIdx.x * 256 + tid) * 8;
    int b = e >> 11;          // / KIN
    int c = e & (KIN - 1);
    const float* src = (c < INW) ? (x + (size_t)b * INW + c)
                                 : (h + (size_t)b * HH + (c - INW));
    float4 v0 = *(const float4*)src;
    float4 v1 = *(const float4*)(src + 4);
    bf16x8 ov;
    ov[0] = (bf16)v0.x; ov[1] = (bf16)v0.y; ov[2] = (bf16)v0.z; ov[3] = (bf16)v0.w;
    ov[4] = (bf16)v1.x; ov[5] = (bf16)v1.y; ov[6] = (bf16)v1.z; ov[7] = (bf16)v1.w;
    *(bf16x8*)(comb + e) = ov;
  } else {                             // ---- Wb: sequential-row shuffle ----
    int w   = blockIdx.x - NCB;        // [0, 1280)
    int nt  = w / 40;
    int rem = w - nt * 40;
    int f   = rem >> 2;                // fragment slot 0..9
    int rp  = rem & 3;                 // row-quarter 0..3
    int q   = f / 5;
    int g   = f - q * 5;               // gate: 0=i 1=f 2=o 3=p0 4=p1
    int kk  = tid >> 2;                // k-chunk of 32
    int kq  = tid & 3;                 // k-quad within chunk
    size_t wbase = ((size_t)(nt * FPG + f) * 64 + kk) * 64 + kq * 16;
#pragma unroll
    for (int r4 = 0; r4 < 4; ++r4) {
      int s    = rp * 4 + r4;          // row-in-fragment 0..15
      int hcol = nt * 32 + q * 16 + s;
      const float* src = (g < 3)
          ? (Wg + (size_t)(g * HH + hcol) * KIN + tid * 8)
          : (Wc + (size_t)(2 * hcol + (g - 3)) * KIN + tid * 8);
      float4 v0 = *(const float4*)src;
      float4 v1 = *(const float4*)(src + 4);
      bf16x8 ov;
      ov[0] = (bf16)v0.x; ov[1] = (bf16)v0.y; ov[2] = (bf16)v0.z; ov[3] = (bf16)v0.w;
      ov[4] = (bf16)v1.x; ov[5] = (bf16)v1.y; ov[6] = (bf16)v1.z; ov[7] = (bf16)v1.w;
      *(bf16x8*)(Wb + (wbase + s) * 8) = ov;
    }
  }
}

// ---------------------------------------------------------------------------
// 2. Fused GEMM + LSTM epilogue. R11 = R10 + T4 counted vmcnt.
//    R10 post-mortem: 4 waves/SIMD + 2-phase dbuf reached 850 TF, MfmaUtil
//    39%; the remaining structural wait is __syncthreads' implicit vmcnt(0),
//    which drains the JUST-ISSUED t+1 prefetch at every iteration (~100-300
//    cyc exposed x 32 iters). Replace with:
//      STAGE(t+1) ; vmcnt(4|5 per role) ; s_barrier ; COMPUTE(t) ; s_barrier
//    The counted wait covers only tile-t's loads (long landed); t+1 stays in
//    flight across the barrier (T4/m218). Second raw barrier protects the
//    read-before-overwrite hazard (next iter's STAGE targets buffer cur);
//    write-side safety = DMA issued after that barrier in program order.
//    vmcnt counts are exact: loop body has no other VMEM (A-waves 4 gld_lds,
//    B-waves 5; scalar loads count lgkm). sched_barrier(0) after each
//    barrier pins compiler ordering (rule #18). R8's null for this technique
//    was at 2 waves/SIMD where occupancy bound; regime now correct.
// ---------------------------------------------------------------------------
#define ASZ  8192      // A elems per buffer (16 KB)
#define BSZ  10240     // B elems per buffer (20 KB)
#define BUF  (ASZ + BSZ)

__global__ __launch_bounds__(512, 4) void gemm_fused(
    const bf16* __restrict__ A, const bf16* __restrict__ Bm,
    const float* __restrict__ c_prev, const float* __restrict__ bg,
    const float* __restrict__ bc, const float* __restrict__ W1,
    const float* __restrict__ b1, const float* __restrict__ W2,
    const float* __restrict__ b2, float* __restrict__ h_next,
    float* __restrict__ c_next) {
  __shared__ bf16 sh[2 * BUF];     // 72 KB: two {A 16K + B 20K} buffers

  const int tid  = threadIdx.x;
  const int wave = tid >> 6;
  const int lane = tid & 63;

  // R5 XCD swizzle (proven): 1024 blocks, 8 XCDs, 128 blocks/XCD, m fastest.
  const int bid = blockIdx.y * gridDim.x + blockIdx.x;
  const int swz = (bid & 7) * 128 + (bid >> 3);
  const int m0  = (swz & 31) * 128;
  const int nt  = swz >> 5;

  const int wm = (wave >> 1) * 32;   // wave row origin (4 row-groups of 32)
  const int q  = wave & 1;           // wave col half: which 16 h's
  const int lr = lane & 15;
  const int qd = lane >> 4;

  floatx4 acc[2][5] = {};

  // ---- STAGE(bb, kt): role-split staging into buffer bb ----
  // waves 0-3: A, 1024 slots (128 rows x 8 chunks), XOR-swizzled
  // waves 4-7: B, 1280 slots (20 chunks of 1 KB), linear
#define STAGE(bb, kt)                                                          \
  {                                                                            \
    if (wave < 4) {                                                            \
      _Pragma("unroll")                                                        \
      for (int j = 0; j < 4; ++j) {                                            \
        int s   = j * 256 + tid;                                               \
        int row = s >> 3;                                                      \
        int c   = (s & 7) ^ (row & 7);                                         \
        GLD16(A + (size_t)(m0 + row) * KIN + (kt) * 64 + c * 8,                \
              sh + (size_t)(bb) * BUF + (size_t)(j * 256 + wave * 64) * 8);    \
      }                                                                        \
    } else {                                                                   \
      int wv = wave - 4;                                                       \
      _Pragma("unroll")                                                        \
      for (int j = 0; j < 5; ++j) {                                            \
        int s   = j * 256 + wv * 64 + lane;                                    \
        int c20 = s >> 6;                                                      \
        int f   = c20 >> 1;                                                    \
        int ks  = c20 & 1;                                                     \
        size_t gchunk = (size_t)(nt * FPG + f) * 64 + ((kt) * 2 + ks);         \
        GLD16(Bm + (gchunk * 64 + lane) * 8,                                   \
              sh + (size_t)(bb) * BUF + ASZ + (size_t)s * 8);                  \
      }                                                                        \
    }                                                                          \
  }

  // ---- COMPUTE(bb): 2 k-steps x 10 MFMA per wave from buffer bb ----
#define COMPUTE(bb)                                                            \
  {                                                                            \
    const bf16* As = sh + (size_t)(bb) * BUF;                                  \
    const bf16* Bs = As + ASZ;                                                 \
    _Pragma("unroll")                                                          \
    for (int ks = 0; ks < 2; ++ks) {                                           \
      bf16x8 af[2];                                                            \
      _Pragma("unroll")                                                        \
      for (int mi = 0; mi < 2; ++mi) {                                         \
        int row  = wm + mi * 16 + lr;                                          \
        int slot = (ks * 4 + qd) ^ (lr & 7);                                   \
        af[mi] = *(const bf16x8*)&As[(row << 6) + (slot << 3)];                \
      }                                                                        \
      bf16x8 bfr[5];                                                           \
      _Pragma("unroll")                                                        \
      for (int ni = 0; ni < 5; ++ni) {                                         \
        int chunk = ((q * 5 + ni) << 1) + ks;                                  \
        bfr[ni] = *(const bf16x8*)&Bs[(chunk << 9) + (lane << 3)];             \
      }                                                                        \
      _Pragma("unroll")                                                        \
      for (int mi = 0; mi < 2; ++mi)                                           \
        _Pragma("unroll")                                                      \
        for (int ni = 0; ni < 5; ++ni)                                         \
          acc[mi][ni] = __builtin_amdgcn_mfma_f32_16x16x32_bf16(               \
              af[mi], bfr[ni], acc[mi][ni], 0, 0, 0);                          \
    }                                                                          \
  }

  // Prologue: stage tile 0 into buffer 0, full drain, barrier.
  STAGE(0, 0);
  asm volatile("s_waitcnt vmcnt(0)" ::: "memory");
  __builtin_amdgcn_s_barrier();
  __builtin_amdgcn_sched_barrier(0);

  // Counted-vmcnt 2-phase pipeline: 31 iterations + tail.
  for (int kt = 0; kt < KIN / 64 - 1; ++kt) {
    const int cur = kt & 1;
    STAGE(cur ^ 1, kt + 1);   // t+1 loads stay in flight across the barrier
    if (wave < 4) asm volatile("s_waitcnt vmcnt(4)" ::: "memory");
    else          asm volatile("s_waitcnt vmcnt(5)" ::: "memory");
    __builtin_amdgcn_s_barrier();            // tile-t buffer fully written
    __builtin_amdgcn_sched_barrier(0);
    COMPUTE(cur);
    __builtin_amdgcn_s_barrier();            // reads done before overwrite
    __builtin_amdgcn_sched_barrier(0);
  }
  // Tail: tile 31's loads must land before the final compute.
  asm volatile("s_waitcnt vmcnt(0)" ::: "memory");
  __builtin_amdgcn_s_barrier();
  __builtin_amdgcn_sched_barrier(0);
  COMPUTE(1);                 // tile 31 (31 & 1 = 1)

  // ---- fused epilogue: all 5 gates of (b, h) live in this lane ----
  const int h   = nt * 32 + q * 16 + lr;
  const float bgi = bg[h];
  const float bgf = bg[HH + h];
  const float bgo = bg[2 * HH + h];
  const float bc0 = bc[2 * h];
  const float bc1 = bc[2 * h + 1];
  const float gb  = b2[0];

  float p0[8], p1[8], ga[8];
#pragma unroll
  for (int mi = 0; mi < 2; ++mi)
#pragma unroll
    for (int r = 0; r < 4; ++r) {
      p0[mi * 4 + r] = acc[mi][3][r] + bc0;
      p1[mi * 4 + r] = acc[mi][4][r] + bc1;
      ga[mi * 4 + r] = gb;
    }
  // inner MLP: k-outer so the 4 uniform weight scalars stay in SGPRs
#pragma unroll
  for (int k = 0; k < KH; ++k) {
    float w0 = W1[2 * k], w1 = W1[2 * k + 1], bk = b1[k], wk = W2[k];
#pragma unroll
    for (int e = 0; e < 8; ++e) {
      float hv = fmaf(p0[e], w0, fmaf(p1[e], w1, bk));
      hv = fmaxf(hv, 0.0f);
      ga[e] = fmaf(hv, wk, ga[e]);
    }
  }

#pragma unroll
  for (int mi = 0; mi < 2; ++mi)
#pragma unroll
    for (int r = 0; r < 4; ++r) {
      int b    = m0 + wm + mi * 16 + qd * 4 + r;
      size_t o = (size_t)b * HH + h;
      float si = 1.0f / (1.0f + __expf(-(acc[mi][0][r] + bgi)));
      float sf = 1.0f / (1.0f + __expf(-(acc[mi][1][r] + bgf)));
      float so = 1.0f / (1.0f + __expf(-(acc[mi][2][r] + bgo)));
      float cn = fmaf(sf, c_prev[o], si * ga[mi * 4 + r]);
      float e2 = __expf(2.0f * cn);          // tanh(cn) = 1 - 2/(e^{2cn}+1)
      float th = 1.0f - 2.0f / (e2 + 1.0f);
      h_next[o] = so * th;
      c_next[o] = cn;
    }
}

// ---------------------------------------------------------------------------
extern "C" void kernel_launch(void* const* d_in, const int* in_sizes, int n_in,
                              void* d_out, int out_size, void* d_ws, size_t ws_size,
                              hipStream_t stream) {
  const float* x      = (const float*)d_in[0];
  const float* h_prev = (const float*)d_in[1];
  const float* c_prev = (const float*)d_in[2];
  const float* Wg     = (const float*)d_in[3];
  const float* bg     = (const float*)d_in[4];
  const float* Wc     = (const float*)d_in[5];
  const float* bc     = (const float*)d_in[6];
  const float* W1     = (const float*)d_in[7];
  const float* b1     = (const float*)d_in[8];
  const float* W2     = (const float*)d_in[9];
  const float* b2     = (const float*)d_in[10];
  float* out = (float*)d_out;

  // workspace layout
  char* ws = (char*)d_ws;
  bf16* comb = (bf16*)ws;                                    // 16 MB
  bf16* Wb   = (bf16*)(ws + (size_t)BB * KIN * 2);           // 20 MB

  // 1. prep (concat + cast + gate-permuted, sequential-read B shuffle)
  prep<<<NCB + NWB, 256, 0, stream>>>(x, h_prev, Wg, Wc, comb, Wb);

  // 2. fused GEMM + epilogue (counted-vmcnt 2-phase, 8-wave geometry)
  dim3 grid(BB / 128, NTG);
  gemm_fused<<<grid, 512, 0, stream>>>(comb, Wb, c_prev, bg, bc, W1, b1, W2,
                                       b2, out, out + (size_t)BB * HH);
}